// Round 3
// baseline (70.084 us; speedup 1.0000x reference)
//
#include <hip/hip_runtime.h>
#include <cstdint>

#define NV 8192
#define CAP 512   // max neighbors tracked per row (mean ~33, 512 is ~84 sigma safe)

// ---------------------------------------------------------------------------
// Probe: decide adjacency storage. Scans the first 64 KB (present under both
// interpretations: uint8 buffer is 64 MB, int32 buffer is 256 MB).
//   int32-bool: every 32-bit word is exactly 0 or 1.
//   uint8-bool: ~0.4% of bytes are 1 at arbitrary byte positions, so ~200
//               words in 64 KB have value >1 (e.g. 0x00010000).
// flag[0] = 1 -> int32 mode, 0 -> uint8 mode. Deterministic.
// ---------------------------------------------------------------------------
__global__ __launch_bounds__(256) void adj_probe(const unsigned int* __restrict__ adj,
                                                 int* __restrict__ flag)
{
    __shared__ int s_bad;
    if (threadIdx.x == 0) s_bad = 0;
    __syncthreads();
    int bad = 0;
    for (int k = threadIdx.x; k < 16384; k += 256) {
        if (adj[k] > 1u) bad = 1;
    }
    if (bad) atomicOr(&s_bad, 1);
    __syncthreads();
    if (threadIdx.x == 0) flag[0] = s_bad ? 0 : 1;
}

__global__ __launch_bounds__(256) void devgnn_kernel(
    const float* __restrict__ x,
    const float* __restrict__ nodes,
    const void* __restrict__ adj_raw,
    const float* __restrict__ Wphi1,   const float* __restrict__ bphi1,
    const float* __restrict__ Wtheta1, const float* __restrict__ btheta1,
    const float* __restrict__ Wphi2,   const float* __restrict__ bphi2,
    const float* __restrict__ Wtheta2, const float* __restrict__ btheta2,
    const float* __restrict__ Wphi3,   const float* __restrict__ bphi3,
    const float* __restrict__ Wtheta3, const float* __restrict__ btheta3,
    const int* __restrict__ mode_flag,
    float* __restrict__ out)
{
    const int i = blockIdx.x;
    const int t = threadIdx.x;

    __shared__ int    s_nb[CAP];
    __shared__ float4 s_p[CAP];
    __shared__ int    s_cnt;
    __shared__ float  sh_h1;
    __shared__ float  sh_agg3;
    __shared__ float4 s_own;

    if (t == 0) s_cnt = 0;
    __syncthreads();

    // ---------- Phase 1: scan adjacency row, compact set columns ----------
    const int mode = mode_flag[0];   // uniform: 1 = int32 elements, 0 = uint8
    if (mode) {
        const int4* row = reinterpret_cast<const int4*>((const int*)adj_raw + (size_t)i * NV);
        #pragma unroll
        for (int r = 0; r < 8; ++r) {
            const int idx4 = t + r * 256;
            const int4 v = row[idx4];
            const int base = idx4 * 4;
            if (v.x) { int p = atomicAdd(&s_cnt, 1); if (p < CAP) s_nb[p] = base + 0; }
            if (v.y) { int p = atomicAdd(&s_cnt, 1); if (p < CAP) s_nb[p] = base + 1; }
            if (v.z) { int p = atomicAdd(&s_cnt, 1); if (p < CAP) s_nb[p] = base + 2; }
            if (v.w) { int p = atomicAdd(&s_cnt, 1); if (p < CAP) s_nb[p] = base + 3; }
        }
    } else {
        const uint4* row = reinterpret_cast<const uint4*>((const unsigned char*)adj_raw + (size_t)i * NV);
        #pragma unroll
        for (int r = 0; r < 2; ++r) {
            const uint4 v = row[t + r * 256];
            const int base = (t + r * 256) * 16;
            unsigned int w[4] = { v.x, v.y, v.z, v.w };
            #pragma unroll
            for (int k = 0; k < 4; ++k) {
                unsigned int wd = w[k];
                while (wd) {
                    const int bit  = __ffs(wd) - 1;
                    const int byte = bit >> 3;
                    wd &= ~(0xFFu << (byte * 8));
                    const int p = atomicAdd(&s_cnt, 1);
                    if (p < CAP) s_nb[p] = base + k * 4 + byte;
                }
            }
        }
    }
    __syncthreads();
    const int cnt = (s_cnt < CAP) ? s_cnt : CAP;

    // ---------- Phase 2: parallel gather of neighbor coordinates ----------
    for (int k = t; k < cnt; k += 256) {
        const int j = s_nb[k];
        float4 c;
        c.x = nodes[3 * j + 0];
        c.y = nodes[3 * j + 1];
        c.z = nodes[3 * j + 2];
        c.w = 0.f;
        s_p[k] = c;
    }
    if (t == 128) {
        float4 c;
        c.x = nodes[3 * i + 0];
        c.y = nodes[3 * i + 1];
        c.z = nodes[3 * i + 2];
        c.w = 0.f;
        s_own = c;
    }
    __syncthreads();

    // ---------- Phase 3: per-channel neighbor mins (66 channels) ----------
    float m = 1e30f, tp_i = 0.f, mw0 = 0.f, mw1 = 0.f, mw2 = 0.f;
    if (t < 66) {
        if (t < 64) {               // layer-2 channel t; Wtheta2 is [3][64] row-major
            mw0 = Wtheta2[0 * 64 + t];
            mw1 = Wtheta2[1 * 64 + t];
            mw2 = Wtheta2[2 * 64 + t];
        } else {                    // t==64 -> theta1, t==65 -> theta3
            const float* Wt = (t == 64) ? Wtheta1 : Wtheta3;
            mw0 = Wt[0]; mw1 = Wt[1]; mw2 = Wt[2];
        }
        #pragma unroll 4
        for (int k = 0; k < cnt; ++k) {
            const float4 c = s_p[k];            // LDS broadcast across lanes
            m = fminf(m, c.x * mw0 + c.y * mw1 + c.z * mw2);
        }
        const float4 q = s_own;
        tp_i = q.x * mw0 + q.y * mw1 + q.z * mw2;

        if (t == 64) {
            const float agg1 = tp_i - m + btheta1[0];
            sh_h1 = fmaxf(0.f, x[i] * Wphi1[0] + bphi1[0] + agg1);
        } else if (t == 65) {
            sh_agg3 = tp_i - m + btheta3[0];
        }
    }
    __syncthreads();

    // ---------- Phase 4: layer-2 epilogue + layer-3 dot + sigmoid ----------
    if (t < 64) {
        const float agg2 = tp_i - m + btheta2[t];
        const float h2 = fmaxf(0.f, sh_h1 * Wphi2[t] + bphi2[t] + agg2);
        float partial = h2 * Wphi3[t];
        #pragma unroll
        for (int d = 32; d >= 1; d >>= 1)
            partial += __shfl_xor(partial, d, 64);
        if (t == 0) {
            const float val = partial + bphi3[0] + sh_agg3;
            out[i] = 1.f / (1.f + expf(-val));
        }
    }
}

extern "C" void kernel_launch(void* const* d_in, const int* in_sizes, int n_in,
                              void* d_out, int out_size, void* d_ws, size_t ws_size,
                              hipStream_t stream) {
    const float* x           = (const float*)d_in[0];
    const float* nodes       = (const float*)d_in[1];
    const void*  adj         = d_in[2];
    const float* Wphi1       = (const float*)d_in[3];
    const float* bphi1       = (const float*)d_in[4];
    const float* Wtheta1     = (const float*)d_in[5];
    const float* btheta1     = (const float*)d_in[6];
    const float* Wphi2       = (const float*)d_in[7];
    const float* bphi2       = (const float*)d_in[8];
    const float* Wtheta2     = (const float*)d_in[9];
    const float* btheta2     = (const float*)d_in[10];
    const float* Wphi3       = (const float*)d_in[11];
    const float* bphi3       = (const float*)d_in[12];
    const float* Wtheta3     = (const float*)d_in[13];
    const float* btheta3     = (const float*)d_in[14];
    float* out    = (float*)d_out;
    int*   d_flag = (int*)d_ws;

    adj_probe<<<1, 256, 0, stream>>>((const unsigned int*)adj, d_flag);
    devgnn_kernel<<<NV, 256, 0, stream>>>(
        x, nodes, adj,
        Wphi1, bphi1, Wtheta1, btheta1,
        Wphi2, bphi2, Wtheta2, btheta2,
        Wphi3, bphi3, Wtheta3, btheta3,
        d_flag, out);
}